// Round 4
// baseline (286.798 us; speedup 1.0000x reference)
//
#include <hip/hip_runtime.h>
#include <hip/hip_bf16.h>

#define N_ 4
#define L_ 1024
#define E_ 1024
#define H_ 32
#define HD_ 32

typedef unsigned short ushort;
typedef __attribute__((ext_vector_type(8))) short short8;   // bf16 x8 MFMA A/B frag
typedef __attribute__((ext_vector_type(4))) short short4v;  // bf16 x4
typedef __attribute__((ext_vector_type(4))) float float4v;  // MFMA C/D frag

__device__ __forceinline__ ushort f2b(float f) {
    __hip_bfloat16 h = __float2bfloat16(f);
    return *reinterpret_cast<ushort*>(&h);
}

// load 8 consecutive fp32, convert to bf16x8 frag
__device__ __forceinline__ short8 cvt8(const float* __restrict__ p) {
    float4v a = *(const float4v*)p;
    float4v b = *(const float4v*)(p + 4);
    short8 r;
    r[0] = (short)f2b(a[0]); r[1] = (short)f2b(a[1]);
    r[2] = (short)f2b(a[2]); r[3] = (short)f2b(a[3]);
    r[4] = (short)f2b(b[0]); r[5] = (short)f2b(b[1]);
    r[6] = (short)f2b(b[2]); r[7] = (short)f2b(b[3]);
    return r;
}

// ---------------------------------------------------------------------------
// Kernel 0: one-time conversions. Wv|Wk|Wq -> w3 bf16; Wo -> bf16;
// mask -> additive bias (0 or -1e30).
// grid 1026 blocks x 256.
// ---------------------------------------------------------------------------
__global__ __launch_bounds__(256) void convert_kernel(
    const float* __restrict__ Wv, const float* __restrict__ Wk,
    const float* __restrict__ Wq, const float* __restrict__ Wo,
    const int* __restrict__ mask,
    ushort* __restrict__ w3, ushort* __restrict__ wo_bf,
    float* __restrict__ bias_f)
{
    const int b = blockIdx.x, t = threadIdx.x;
    if (b == 0) {
        for (int i = t; i < 3 * HD_ * HD_; i += 256) {
            float v = (i < 1024) ? Wv[i] : (i < 2048 ? Wk[i - 1024] : Wq[i - 2048]);
            w3[i] = f2b(v);
        }
    } else if (b == 1) {
        for (int i = t; i < N_ * L_; i += 256)
            bias_f[i] = (mask[i] == 0) ? -1e30f : 0.0f;
    } else {
        int i = (b - 2) * 1024 + t * 4;
        float4v v = *(const float4v*)(Wo + i);
        short4v o;
        o[0] = (short)f2b(v[0]); o[1] = (short)f2b(v[1]);
        o[2] = (short)f2b(v[2]); o[3] = (short)f2b(v[3]);
        *(short4v*)(wo_bf + i) = o;
    }
}

// ---------------------------------------------------------------------------
// Kernel 1: per-head projections via MFMA, no LDS.
// grid (L/64, H, N), block 256 (4 waves; wave = 16-token tile).
// A-frags: direct fp32 loads + cvt. B-frags: direct bf16 loads from w3.
// Outputs bf16: q_ws,k_ws (N,H,L,HD); vt_ws (N,H,HD,L).
// ---------------------------------------------------------------------------
__global__ __launch_bounds__(256) void proj_kernel(
    const float* __restrict__ v_in, const float* __restrict__ k_in,
    const float* __restrict__ q_in, const ushort* __restrict__ w3,
    ushort* __restrict__ vt_ws, ushort* __restrict__ k_ws,
    ushort* __restrict__ q_ws)
{
    const int n = blockIdx.z, h = blockIdx.y, l0 = blockIdx.x * 64;
    const int t = threadIdx.x, wave = t >> 6, lane = t & 63;
    const int m = lane & 15, g = lane >> 4;

    const size_t row = (size_t)(n * L_) + l0 + wave * 16 + m;
    const float* src[3] = {v_in, k_in, q_in};
    short8 A[3];
#pragma unroll
    for (int mat = 0; mat < 3; ++mat)
        A[mat] = cvt8(src[mat] + row * E_ + h * HD_ + g * 8);

    float4v acc[3][2];
#pragma unroll
    for (int mat = 0; mat < 3; ++mat)
#pragma unroll
        for (int dt = 0; dt < 2; ++dt) {
            // B[k=e][n=d]: lane holds W[d = dt*16+m][e = g*8..+7]
            short8 B = *(const short8*)(w3 + mat * 1024 + (dt * 16 + m) * HD_ + g * 8);
            float4v z = float4v{0.f, 0.f, 0.f, 0.f};
            acc[mat][dt] = __builtin_amdgcn_mfma_f32_16x16x32_bf16(A[mat], B, z, 0, 0, 0);
        }

    const size_t obase = (size_t)(n * H_ + h) * L_;
    const size_t vb = (size_t)(n * H_ + h) * HD_ * L_;
#pragma unroll
    for (int dt = 0; dt < 2; ++dt)
#pragma unroll
        for (int r = 0; r < 4; ++r) {
            int tok = l0 + wave * 16 + g * 4 + r;   // D row -> token
            int d = dt * 16 + m;                     // D col -> out dim
            k_ws[(obase + tok) * HD_ + d] = f2b(acc[1][dt][r]);
            q_ws[(obase + tok) * HD_ + d] = f2b(acc[2][dt][r]);
            vt_ws[vb + (size_t)d * L_ + tok] = f2b(acc[0][dt][r]);
        }
}

// ---------------------------------------------------------------------------
// Kernel 2: attention, barrier-free. grid (L/64, H, N), block 256.
// Wave owns 16 q-rows. Per 64-token chunk: 4 QK MFMA (K B-frags direct from
// global), additive mask bias, p=exp2 (no max-sub: |s*scale|<~1, exact up to
// rounding), P -> wave-private LDS transpose, 4 PV MFMA (V^T B-frags direct
// from global). Row-sum deferred to ONE epilogue shuffle-reduce.
// ---------------------------------------------------------------------------
__global__ __launch_bounds__(256) void attn_kernel(
    const ushort* __restrict__ q_ws, const ushort* __restrict__ k_ws,
    const ushort* __restrict__ vt_ws, const float* __restrict__ bias_f,
    ushort* __restrict__ x_ws)
{
    const int n = blockIdx.z, h = blockIdx.y, q0 = blockIdx.x * 64;
    const int t = threadIdx.x, wave = t >> 6, lane = t & 63;
    const int m = lane & 15, g = lane >> 4;

    __shared__ ushort sP[4][16][72];   // wave-private; stride 72 -> 16B-aligned rows

    const size_t base = (size_t)(n * H_ + h) * L_;
    const ushort* kb_p = k_ws + base * HD_;
    const ushort* vb_p = vt_ws + (size_t)(n * H_ + h) * HD_ * L_;
    const float* bias_p = bias_f + n * L_;

    // persistent Q A-frag: A[m][k=g*8+j]
    short8 qf = *(const short8*)(q_ws + (base + q0 + wave * 16 + m) * HD_ + g * 8);

    float4v O[2];
    O[0] = float4v{0.f, 0.f, 0.f, 0.f};
    O[1] = float4v{0.f, 0.f, 0.f, 0.f};
    float rs[4] = {0.f, 0.f, 0.f, 0.f};
    const float k1 = 0.03125f * 1.44269504f;   // (1/sqrt(E)) * log2(e)

    for (int tok0 = 0; tok0 < L_; tok0 += 64) {
#pragma unroll
        for (int nb = 0; nb < 4; ++nb) {
            // K B-frag direct: B[k=e][n=tok]: lane holds K[tok0+nb*16+m][g*8..]
            short8 kf = *(const short8*)(kb_p + (size_t)(tok0 + nb * 16 + m) * HD_ + g * 8);
            float4v z = float4v{0.f, 0.f, 0.f, 0.f};
            float4v s = __builtin_amdgcn_mfma_f32_16x16x32_bf16(qf, kf, z, 0, 0, 0);
            float bias = bias_p[tok0 + nb * 16 + m];
#pragma unroll
            for (int r = 0; r < 4; ++r) {
                float p = exp2f(fmaf(s[r], k1, bias));
                rs[r] += p;
                sP[wave][g * 4 + r][nb * 16 + m] = f2b(p);   // D -> A-layout transpose
            }
        }
        // PV: O += P(16x64) * V(64x32); same-wave LDS RAW/WAR is in-order
#pragma unroll
        for (int kb = 0; kb < 2; ++kb) {
            short8 af = *(const short8*)&sP[wave][m][kb * 32 + g * 8];
#pragma unroll
            for (int db = 0; db < 2; ++db) {
                short8 vf = *(const short8*)(vb_p + (size_t)(db * 16 + m) * L_ + tok0 + kb * 32 + g * 8);
                O[db] = __builtin_amdgcn_mfma_f32_16x16x32_bf16(af, vf, O[db], 0, 0, 0);
            }
        }
    }

    // epilogue: single row-sum reduction (row spans 16 lanes of the quad-group)
#pragma unroll
    for (int r = 0; r < 4; ++r)
#pragma unroll
        for (int off = 1; off < 16; off <<= 1)
            rs[r] += __shfl_xor(rs[r], off, 64);

#pragma unroll
    for (int r = 0; r < 4; ++r) {
        float inv = 1.f / rs[r];
        size_t row = (size_t)n * L_ + q0 + wave * 16 + g * 4 + r;
#pragma unroll
        for (int db = 0; db < 2; ++db)
            x_ws[row * E_ + h * HD_ + db * 16 + m] = f2b(O[db][r] * inv);
    }
}

// ---------------------------------------------------------------------------
// Kernel 3: C = X(bf16 4096x1024) @ Wo^T(bf16) + bo, fp32 out. No LDS:
// A and B frags loaded directly from global (L2-resident reuse).
// grid (E/64, NL/128), block 256 (4 waves; wave = 16 cols, 128 rows).
// ---------------------------------------------------------------------------
__global__ __launch_bounds__(256) void out_gemm_kernel(
    const ushort* __restrict__ X, const ushort* __restrict__ wo_bf,
    const float* __restrict__ bo, float* __restrict__ C)
{
    const int j0 = blockIdx.x * 64;
    const int i0 = blockIdx.y * 128;
    const int t = threadIdx.x, wave = t >> 6, lane = t & 63;
    const int m = lane & 15, g = lane >> 4;

    float4v acc[8];
#pragma unroll
    for (int mb = 0; mb < 8; ++mb) acc[mb] = float4v{0.f, 0.f, 0.f, 0.f};

    const ushort* brow = wo_bf + (size_t)(j0 + wave * 16 + m) * E_;
    for (int k0 = 0; k0 < E_; k0 += 32) {
        short8 bf = *(const short8*)(brow + k0 + g * 8);
#pragma unroll
        for (int mb = 0; mb < 8; ++mb) {
            short8 af = *(const short8*)(X + (size_t)(i0 + mb * 16 + m) * E_ + k0 + g * 8);
            acc[mb] = __builtin_amdgcn_mfma_f32_16x16x32_bf16(af, bf, acc[mb], 0, 0, 0);
        }
    }

    int col = j0 + wave * 16 + m;
    float bias = bo[col];
#pragma unroll
    for (int mb = 0; mb < 8; ++mb)
#pragma unroll
        for (int r = 0; r < 4; ++r) {
            int rowi = i0 + mb * 16 + g * 4 + r;
            C[(size_t)rowi * E_ + col] = acc[mb][r] + bias;
        }
}

// ---------------------------------------------------------------------------
extern "C" void kernel_launch(void* const* d_in, const int* in_sizes, int n_in,
                              void* d_out, int out_size, void* d_ws, size_t ws_size,
                              hipStream_t stream) {
    const float* values = (const float*)d_in[0];
    const float* keys   = (const float*)d_in[1];
    const float* query  = (const float*)d_in[2];
    const int*   mask   = (const int*)d_in[3];
    const float* Wv     = (const float*)d_in[4];
    const float* Wk     = (const float*)d_in[5];
    const float* Wq     = (const float*)d_in[6];
    const float* Wo     = (const float*)d_in[7];
    const float* bo     = (const float*)d_in[8];
    float* out = (float*)d_out;

    const size_t M4 = (size_t)N_ * H_ * L_ * HD_;   // 4 Mi elements
    ushort* q_ws   = (ushort*)d_ws;
    ushort* k_ws   = q_ws + M4;
    ushort* vt_ws  = k_ws + M4;
    ushort* x_ws   = vt_ws + M4;
    ushort* wo_bf  = x_ws + M4;                     // 1 Mi
    ushort* w3     = wo_bf + (size_t)E_ * E_;       // 3072
    float*  bias_f = (float*)(w3 + 3 * HD_ * HD_);  // 4096 floats (offset 16B-aligned)

    convert_kernel<<<dim3(2 + (E_ * E_) / 1024), 256, 0, stream>>>(
        Wv, Wk, Wq, Wo, mask, w3, wo_bf, bias_f);

    proj_kernel<<<dim3(L_ / 64, H_, N_), 256, 0, stream>>>(
        values, keys, query, w3, vt_ws, k_ws, q_ws);

    attn_kernel<<<dim3(L_ / 64, H_, N_), 256, 0, stream>>>(
        q_ws, k_ws, vt_ws, bias_f, x_ws);

    out_gemm_kernel<<<dim3(E_ / 64, (N_ * L_) / 128), 256, 0, stream>>>(
        x_ws, wo_bf, bo, out);
}

// Round 5
// 229.205 us; speedup vs baseline: 1.2513x; 1.2513x over previous
//
#include <hip/hip_runtime.h>
#include <hip/hip_bf16.h>

#define N_ 4
#define L_ 1024
#define E_ 1024
#define H_ 32
#define HD_ 32

typedef unsigned short ushort;
typedef __attribute__((ext_vector_type(8))) short short8;   // bf16 x8 MFMA A/B frag
typedef __attribute__((ext_vector_type(4))) short short4v;  // bf16 x4
typedef __attribute__((ext_vector_type(4))) float float4v;  // MFMA C/D frag

__device__ __forceinline__ ushort f2b(float f) {
    __hip_bfloat16 h = __float2bfloat16(f);
    return *reinterpret_cast<ushort*>(&h);
}

// load 8 consecutive fp32, convert to bf16x8 frag
__device__ __forceinline__ short8 cvt8(const float* __restrict__ p) {
    float4v a = *(const float4v*)p;
    float4v b = *(const float4v*)(p + 4);
    short8 r;
    r[0] = (short)f2b(a[0]); r[1] = (short)f2b(a[1]);
    r[2] = (short)f2b(a[2]); r[3] = (short)f2b(a[3]);
    r[4] = (short)f2b(b[0]); r[5] = (short)f2b(b[1]);
    r[6] = (short)f2b(b[2]); r[7] = (short)f2b(b[3]);
    return r;
}

// ---------------------------------------------------------------------------
// Kernel 0: one-time conversions. Wv|Wk|Wq -> w3 bf16; Wo -> bf16;
// mask -> additive bias (0 or -1e30).
// ---------------------------------------------------------------------------
__global__ __launch_bounds__(256) void convert_kernel(
    const float* __restrict__ Wv, const float* __restrict__ Wk,
    const float* __restrict__ Wq, const float* __restrict__ Wo,
    const int* __restrict__ mask,
    ushort* __restrict__ w3, ushort* __restrict__ wo_bf,
    float* __restrict__ bias_f)
{
    const int b = blockIdx.x, t = threadIdx.x;
    if (b == 0) {
        for (int i = t; i < 3 * HD_ * HD_; i += 256) {
            float v = (i < 1024) ? Wv[i] : (i < 2048 ? Wk[i - 1024] : Wq[i - 2048]);
            w3[i] = f2b(v);
        }
    } else if (b == 1) {
        for (int i = t; i < N_ * L_; i += 256)
            bias_f[i] = (mask[i] == 0) ? -1e30f : 0.0f;
    } else {
        int i = (b - 2) * 1024 + t * 4;
        float4v v = *(const float4v*)(Wo + i);
        short4v o;
        o[0] = (short)f2b(v[0]); o[1] = (short)f2b(v[1]);
        o[2] = (short)f2b(v[2]); o[3] = (short)f2b(v[3]);
        *(short4v*)(wo_bf + i) = o;
    }
}

// ---------------------------------------------------------------------------
// Kernel 1: per-head projections via MFMA, no LDS. (unchanged from R4)
// grid (L/64, H, N), block 256.
// ---------------------------------------------------------------------------
__global__ __launch_bounds__(256) void proj_kernel(
    const float* __restrict__ v_in, const float* __restrict__ k_in,
    const float* __restrict__ q_in, const ushort* __restrict__ w3,
    ushort* __restrict__ vt_ws, ushort* __restrict__ k_ws,
    ushort* __restrict__ q_ws)
{
    const int n = blockIdx.z, h = blockIdx.y, l0 = blockIdx.x * 64;
    const int t = threadIdx.x, wave = t >> 6, lane = t & 63;
    const int m = lane & 15, g = lane >> 4;

    const size_t row = (size_t)(n * L_) + l0 + wave * 16 + m;
    const float* src[3] = {v_in, k_in, q_in};
    short8 A[3];
#pragma unroll
    for (int mat = 0; mat < 3; ++mat)
        A[mat] = cvt8(src[mat] + row * E_ + h * HD_ + g * 8);

    float4v acc[3][2];
#pragma unroll
    for (int mat = 0; mat < 3; ++mat)
#pragma unroll
        for (int dt = 0; dt < 2; ++dt) {
            short8 B = *(const short8*)(w3 + mat * 1024 + (dt * 16 + m) * HD_ + g * 8);
            float4v z = float4v{0.f, 0.f, 0.f, 0.f};
            acc[mat][dt] = __builtin_amdgcn_mfma_f32_16x16x32_bf16(A[mat], B, z, 0, 0, 0);
        }

    const size_t obase = (size_t)(n * H_ + h) * L_;
    const size_t vb = (size_t)(n * H_ + h) * HD_ * L_;
#pragma unroll
    for (int dt = 0; dt < 2; ++dt)
#pragma unroll
        for (int r = 0; r < 4; ++r) {
            int tok = l0 + wave * 16 + g * 4 + r;
            int d = dt * 16 + m;
            k_ws[(obase + tok) * HD_ + d] = f2b(acc[1][dt][r]);
            q_ws[(obase + tok) * HD_ + d] = f2b(acc[2][dt][r]);
            vt_ws[vb + (size_t)d * L_ + tok] = f2b(acc[0][dt][r]);
        }
}

// ---------------------------------------------------------------------------
// Kernel 2: attention, barrier-free, XCD-swizzled.
// 1-D grid of 2048 blocks: B = (head>>3)*128 + qt*8 + (head&7), so all 16
// q-tiles of one head share B%8 -> same XCD -> K/V stay L2-resident.
// Otherwise identical to R4.
// ---------------------------------------------------------------------------
__global__ __launch_bounds__(256) void attn_kernel(
    const ushort* __restrict__ q_ws, const ushort* __restrict__ k_ws,
    const ushort* __restrict__ vt_ws, const float* __restrict__ bias_f,
    ushort* __restrict__ x_ws)
{
    const int B = blockIdx.x;
    const int head = ((B >> 7) << 3) + (B & 7);   // 0..127
    const int qt = (B >> 3) & 15;
    const int n = head >> 5, h = head & 31, q0 = qt * 64;

    const int t = threadIdx.x, wave = t >> 6, lane = t & 63;
    const int m = lane & 15, g = lane >> 4;

    __shared__ ushort sP[4][16][72];   // wave-private; 16B-aligned rows

    const size_t base = (size_t)(n * H_ + h) * L_;
    const ushort* kb_p = k_ws + base * HD_;
    const ushort* vb_p = vt_ws + (size_t)(n * H_ + h) * HD_ * L_;
    const float* bias_p = bias_f + n * L_;

    short8 qf = *(const short8*)(q_ws + (base + q0 + wave * 16 + m) * HD_ + g * 8);

    float4v O[2];
    O[0] = float4v{0.f, 0.f, 0.f, 0.f};
    O[1] = float4v{0.f, 0.f, 0.f, 0.f};
    float rs[4] = {0.f, 0.f, 0.f, 0.f};
    const float k1 = 0.03125f * 1.44269504f;   // (1/sqrt(E)) * log2(e)

    for (int tok0 = 0; tok0 < L_; tok0 += 64) {
#pragma unroll
        for (int nb = 0; nb < 4; ++nb) {
            short8 kf = *(const short8*)(kb_p + (size_t)(tok0 + nb * 16 + m) * HD_ + g * 8);
            float4v z = float4v{0.f, 0.f, 0.f, 0.f};
            float4v s = __builtin_amdgcn_mfma_f32_16x16x32_bf16(qf, kf, z, 0, 0, 0);
            float bias = bias_p[tok0 + nb * 16 + m];
#pragma unroll
            for (int r = 0; r < 4; ++r) {
                float p = exp2f(fmaf(s[r], k1, bias));
                rs[r] += p;
                sP[wave][g * 4 + r][nb * 16 + m] = f2b(p);   // D -> A-layout transpose
            }
        }
#pragma unroll
        for (int kb = 0; kb < 2; ++kb) {
            short8 af = *(const short8*)&sP[wave][m][kb * 32 + g * 8];
#pragma unroll
            for (int db = 0; db < 2; ++db) {
                short8 vf = *(const short8*)(vb_p + (size_t)(db * 16 + m) * L_ + tok0 + kb * 32 + g * 8);
                O[db] = __builtin_amdgcn_mfma_f32_16x16x32_bf16(af, vf, O[db], 0, 0, 0);
            }
        }
    }

#pragma unroll
    for (int r = 0; r < 4; ++r)
#pragma unroll
        for (int off = 1; off < 16; off <<= 1)
            rs[r] += __shfl_xor(rs[r], off, 64);

#pragma unroll
    for (int r = 0; r < 4; ++r) {
        float inv = 1.f / rs[r];
        size_t row = (size_t)n * L_ + q0 + wave * 16 + g * 4 + r;
#pragma unroll
        for (int db = 0; db < 2; ++db)
            x_ws[row * E_ + h * HD_ + db * 16 + m] = f2b(O[db][r] * inv);
    }
}

// ---------------------------------------------------------------------------
// Kernel 3: C = X(bf16 4096x1024) @ Wo^T(bf16) + bo, fp32 out.
// LDS-staged 128x64 tile, BK=64. 512 blocks, XCD-swizzled so all 16 j-tiles
// of an i-tile share an XCD (X fetched from HBM once; Wo L2-resident).
// 4 waves: wave (wr,wc) computes rows wr*64..+64, cols wc*32..+32.
// ---------------------------------------------------------------------------
__global__ __launch_bounds__(256) void out_gemm_kernel(
    const ushort* __restrict__ X, const ushort* __restrict__ wo_bf,
    const float* __restrict__ bo, float* __restrict__ C)
{
    const int B = blockIdx.x;
    const int it = ((B >> 7) << 3) + (B & 7);   // 0..31
    const int jt = (B >> 3) & 15;               // 0..15
    const int i0 = it * 128, j0 = jt * 64;

    const int t = threadIdx.x, wave = t >> 6, lane = t & 63;
    const int m = lane & 15, g = lane >> 4;
    const int wr = wave >> 1, wc = wave & 1;

    __shared__ ushort sA[128][72];   // stride 72 ushorts = 144B: 16B-aligned, 2-way banks
    __shared__ ushort sB[64][72];

    float4v acc[4][2];
#pragma unroll
    for (int mb = 0; mb < 4; ++mb)
#pragma unroll
        for (int nb = 0; nb < 2; ++nb) acc[mb][nb] = float4v{0.f, 0.f, 0.f, 0.f};

    const int r0 = t >> 3;          // 0..31
    const int kc = (t & 7) * 8;     // 0..56

    for (int k0 = 0; k0 < E_; k0 += 64) {
        __syncthreads();
#pragma unroll
        for (int p = 0; p < 4; ++p)
            *(short8*)&sA[r0 + p * 32][kc] =
                *(const short8*)(X + (size_t)(i0 + r0 + p * 32) * E_ + k0 + kc);
#pragma unroll
        for (int p = 0; p < 2; ++p)
            *(short8*)&sB[r0 + p * 32][kc] =
                *(const short8*)(wo_bf + (size_t)(j0 + r0 + p * 32) * E_ + k0 + kc);
        __syncthreads();
#pragma unroll
        for (int kb = 0; kb < 2; ++kb) {
            short8 bfr0 = *(const short8*)&sB[wc * 32 + m][kb * 32 + g * 8];
            short8 bfr1 = *(const short8*)&sB[wc * 32 + 16 + m][kb * 32 + g * 8];
#pragma unroll
            for (int mb = 0; mb < 4; ++mb) {
                short8 afr = *(const short8*)&sA[wr * 64 + mb * 16 + m][kb * 32 + g * 8];
                acc[mb][0] = __builtin_amdgcn_mfma_f32_16x16x32_bf16(afr, bfr0, acc[mb][0], 0, 0, 0);
                acc[mb][1] = __builtin_amdgcn_mfma_f32_16x16x32_bf16(afr, bfr1, acc[mb][1], 0, 0, 0);
            }
        }
    }

#pragma unroll
    for (int nb = 0; nb < 2; ++nb) {
        int col = j0 + wc * 32 + nb * 16 + m;
        float bias = bo[col];
#pragma unroll
        for (int mb = 0; mb < 4; ++mb)
#pragma unroll
            for (int r = 0; r < 4; ++r) {
                int rowi = i0 + wr * 64 + mb * 16 + g * 4 + r;
                C[(size_t)rowi * E_ + col] = acc[mb][nb][r] + bias;
            }
    }
}

// ---------------------------------------------------------------------------
extern "C" void kernel_launch(void* const* d_in, const int* in_sizes, int n_in,
                              void* d_out, int out_size, void* d_ws, size_t ws_size,
                              hipStream_t stream) {
    const float* values = (const float*)d_in[0];
    const float* keys   = (const float*)d_in[1];
    const float* query  = (const float*)d_in[2];
    const int*   mask   = (const int*)d_in[3];
    const float* Wv     = (const float*)d_in[4];
    const float* Wk     = (const float*)d_in[5];
    const float* Wq     = (const float*)d_in[6];
    const float* Wo     = (const float*)d_in[7];
    const float* bo     = (const float*)d_in[8];
    float* out = (float*)d_out;

    const size_t M4 = (size_t)N_ * H_ * L_ * HD_;   // 4 Mi elements
    ushort* q_ws   = (ushort*)d_ws;
    ushort* k_ws   = q_ws + M4;
    ushort* vt_ws  = k_ws + M4;
    ushort* x_ws   = vt_ws + M4;
    ushort* wo_bf  = x_ws + M4;                     // 1 Mi
    ushort* w3     = wo_bf + (size_t)E_ * E_;       // 3072
    float*  bias_f = (float*)(w3 + 3 * HD_ * HD_);  // 4096 floats

    convert_kernel<<<dim3(2 + (E_ * E_) / 1024), 256, 0, stream>>>(
        Wv, Wk, Wq, Wo, mask, w3, wo_bf, bias_f);

    proj_kernel<<<dim3(L_ / 64, H_, N_), 256, 0, stream>>>(
        values, keys, query, w3, vt_ws, k_ws, q_ws);

    attn_kernel<<<dim3(2048), 256, 0, stream>>>(
        q_ws, k_ws, vt_ws, bias_f, x_ws);

    out_gemm_kernel<<<dim3(512), 256, 0, stream>>>(
        x_ws, wo_bf, bo, out);
}